// Round 5
// baseline (296.544 us; speedup 1.0000x reference)
//
#include <hip/hip_runtime.h>

// Problem constants (fixed by the reference)
#define B_TOT   16384
#define N_CAP   32
#define J_CAP   16
#define I_DIM   8
#define D_DIM   16

#define NTH     512          // (n 0..31) x (j 0..15); j = low 4 lane bits
#define NBLK    512
#define BPB     (B_TOT/NBLK) // 32 b per block
#define CHUNK   2            // b per chunk; u lives in regs across softmax
#define NCHUNK  (BPB/CHUNK)  // 16

// DPP exchange-add / exchange-max.
// quad_perm xor1 = 0xB1, quad_perm xor2 = 0x4E,
// row_ror:1/2/4/8 = 0x121/0x122/0x124/0x128 (16-lane rows; ror:8 == xor8)
template<int CTRL>
__device__ __forceinline__ float dpp_xadd(float v) {
    int m = __builtin_amdgcn_update_dpp(0, __float_as_int(v), CTRL, 0xF, 0xF, true);
    return v + __int_as_float(m);
}
template<int CTRL>
__device__ __forceinline__ float dpp_xmax(float v) {
    int m = __builtin_amdgcn_update_dpp(0, __float_as_int(v), CTRL, 0xF, 0xF, true);
    return fmaxf(v, __int_as_float(m));
}
// xor4 within 16-lane group via ds_swizzle (BitMode xor_mask=4, and_mask=0x1F)
__device__ __forceinline__ float swz_xor4(float v) {
    return __int_as_float(__builtin_amdgcn_ds_swizzle(__float_as_int(v), 0x101F));
}

// Explicit AGPR residency: values parked with v_accvgpr_write cannot be
// rematerialized as memory loads by the compiler. R3/R4 counters showed
// VGPR_Count=104 < 128 live W values => W was re-fetched from L2 inside the
// chunk loop; this takes residency out of the register allocator's hands.
__device__ __forceinline__ void agpr_put(float& slot, float v) {
    asm volatile("v_accvgpr_write_b32 %0, %1" : "=a"(slot) : "v"(v));
}
__device__ __forceinline__ float agpr_get(const float& slot) {
    float v;
    asm volatile("v_accvgpr_read_b32 %0, %1" : "=v"(v) : "a"(slot));
    return v;
}

__global__ __launch_bounds__(NTH, 2)
void caps_v5(const float* __restrict__ X,     // (B, J, I)
             const float* __restrict__ Wg,    // (N, J, I, D)
             const float* __restrict__ Bias,  // (N, J, 1)
             float* __restrict__ Out)         // (B, N, D)
{
    // logits/c, double-buffered by chunk parity: [par][cb*544 + n*17 + j]
    __shared__ float sL[2][CHUNK * 544];

    const int t = threadIdx.x;
    const int j = t & 15;

    // ---- W[n,j,:,:] -> 128 AGPRs; t*128 is contiguous & coalesced ----
    float Wa[8][16];   // lives in AGPRs via agpr_put/agpr_get
    {
        const float4* wp = reinterpret_cast<const float4*>(Wg + (size_t)t * 128);
        #pragma unroll
        for (int i = 0; i < 8; ++i)
            #pragma unroll
            for (int q = 0; q < 4; ++q) {
                float4 v = wp[i * 4 + q];
                agpr_put(Wa[i][q*4+0], v.x);
                agpr_put(Wa[i][q*4+1], v.y);
                agpr_put(Wa[i][q*4+2], v.z);
                agpr_put(Wa[i][q*4+3], v.w);
            }
    }

    // softmax role (threads 0..127): (cb, j, n-quarter)
    const int sm_cb = t >> 6, sm_j = (t >> 2) & 15, sm_nq = t & 3;
    float biasr[8];
    if (t < 128) {
        #pragma unroll
        for (int k = 0; k < 8; ++k)
            biasr[k] = Bias[(sm_nq * 8 + k) * 16 + sm_j];
    }

    const int bblk = blockIdx.x * BPB;

    // x pipeline: preload chunk 0
    float xc[CHUNK][8];
    #pragma unroll
    for (int cb = 0; cb < CHUNK; ++cb) {
        const float4* xp = reinterpret_cast<const float4*>(
            X + (size_t)(bblk + cb) * 128 + j * 8);
        float4 xa = xp[0], xb = xp[1];
        xc[cb][0]=xa.x; xc[cb][1]=xa.y; xc[cb][2]=xa.z; xc[cb][3]=xa.w;
        xc[cb][4]=xb.x; xc[cb][5]=xb.y; xc[cb][6]=xb.z; xc[cb][7]=xb.w;
    }

    #pragma unroll 1
    for (int ch = 0; ch < NCHUNK; ++ch) {
        float* Ls = sL[ch & 1];
        const int b0 = bblk + ch * CHUNK;
        float u[CHUNK][16];

        // ============ phase 1a: u FMAs (W from AGPRs, x from regs) ============
        #pragma unroll
        for (int i = 0; i < 8; ++i) {
            float w[16];
            #pragma unroll
            for (int z = 0; z < 16; ++z) w[z] = agpr_get(Wa[i][z]);
            if (i == 0) {
                #pragma unroll
                for (int z = 0; z < 16; ++z) {
                    u[0][z] = xc[0][0] * w[z];
                    u[1][z] = xc[1][0] * w[z];
                }
            } else {
                #pragma unroll
                for (int z = 0; z < 16; ++z) {
                    u[0][z] = fmaf(xc[0][i], w[z], u[0][z]);
                    u[1][z] = fmaf(xc[1][i], w[z], u[1][z]);
                }
            }
        }

        // ============ prefetch next chunk's x (latency hidden by 1b) ============
        {
            const int chn = (ch + 1 < NCHUNK) ? ch + 1 : 0;   // wrap: harmless reload
            const int bn = bblk + chn * CHUNK;
            #pragma unroll
            for (int cb = 0; cb < CHUNK; ++cb) {
                const float4* xp = reinterpret_cast<const float4*>(
                    X + (size_t)(bn + cb) * 128 + j * 8);
                float4 xa = xp[0], xb = xp[1];
                xc[cb][0]=xa.x; xc[cb][1]=xa.y; xc[cb][2]=xa.z; xc[cb][3]=xa.w;
                xc[cb][4]=xb.x; xc[cb][5]=xb.y; xc[cb][6]=xb.z; xc[cb][7]=xb.w;
            }
        }

        // ============ phase 1b: usum allreduce + logits ============
        #pragma unroll
        for (int cb = 0; cb < CHUNK; ++cb) {
            float us[16];
            #pragma unroll
            for (int z = 0; z < 16; ++z) us[z] = dpp_xadd<0x128>(u[cb][z]);
            #pragma unroll
            for (int z = 0; z < 16; ++z) us[z] = dpp_xadd<0x124>(us[z]);
            #pragma unroll
            for (int z = 0; z < 16; ++z) us[z] = dpp_xadd<0x122>(us[z]);
            #pragma unroll
            for (int z = 0; z < 16; ++z) us[z] = dpp_xadd<0x121>(us[z]);

            float lg0 = 0.f, lg1 = 0.f;
            #pragma unroll
            for (int z = 0; z < 8; ++z) {
                lg0 = fmaf(u[cb][z],     us[z],     lg0);
                lg1 = fmaf(u[cb][z + 8], us[z + 8], lg1);
            }
            Ls[cb * 544 + (t >> 4) * 17 + j] = (lg0 + lg1) * 0.25f;  // /sqrt(D)
        }
        __syncthreads();

        // ============ softmax over n (2 waves) ============
        if (t < 128) {
            float* Lb = Ls + sm_cb * 544;
            float l[8];
            #pragma unroll
            for (int k = 0; k < 8; ++k) l[k] = Lb[(sm_nq * 8 + k) * 17 + sm_j];
            float m = l[0];
            #pragma unroll
            for (int k = 1; k < 8; ++k) m = fmaxf(m, l[k]);
            m = dpp_xmax<0xB1>(m);            // allreduce max over the 4 nq lanes
            m = dpp_xmax<0x4E>(m);
            float e[8], Z = 0.f;
            #pragma unroll
            for (int k = 0; k < 8; ++k) { e[k] = __expf(l[k] - m); Z += e[k]; }
            Z = dpp_xadd<0xB1>(Z);
            Z = dpp_xadd<0x4E>(Z);
            const float inv = __builtin_amdgcn_rcpf(Z);
            #pragma unroll
            for (int k = 0; k < 8; ++k)
                Lb[(sm_nq * 8 + k) * 17 + sm_j] = fmaf(e[k], inv, biasr[k]);
        }
        __syncthreads();

        // ============ phase 2: s[b,n,z] = sum_j c * u ============
        #pragma unroll
        for (int cb = 0; cb < CHUNK; ++cb) {
            const float c = Ls[cb * 544 + (t >> 4) * 17 + j];
            float p[16];
            #pragma unroll
            for (int z = 0; z < 16; ++z) p[z] = c * u[cb][z];

            // reduce-scatter over 16 j-lanes; lane j exits with s[z=j]
            float s8[16];
            #pragma unroll
            for (int k = 0; k < 16; ++k) s8[k] = dpp_xadd<0x128>(p[k]);
            float a8[8];
            #pragma unroll
            for (int k = 0; k < 8; ++k) a8[k] = (j & 8) ? s8[k + 8] : s8[k];
            float s2[8];
            #pragma unroll
            for (int k = 0; k < 8; ++k) s2[k] = dpp_xadd<0x4E>(a8[k]);
            float a2[4];
            a2[0] = (j & 2) ? s2[2] : s2[0];
            a2[1] = (j & 2) ? s2[3] : s2[1];
            a2[2] = (j & 2) ? s2[6] : s2[4];
            a2[3] = (j & 2) ? s2[7] : s2[5];
            float s1[4];
            #pragma unroll
            for (int k = 0; k < 4; ++k) s1[k] = dpp_xadd<0xB1>(a2[k]);
            float a1[2];
            a1[0] = (j & 1) ? s1[1] : s1[0];
            a1[1] = (j & 1) ? s1[3] : s1[2];
            float f0 = a1[0] + swz_xor4(a1[0]);
            float f1 = a1[1] + swz_xor4(a1[1]);
            float s = (j & 4) ? f1 : f0;

            Out[(size_t)(b0 + cb) * 512 + t] = s;   // b*512 + n*16 + z, coalesced
        }
    }
}

extern "C" void kernel_launch(void* const* d_in, const int* in_sizes, int n_in,
                              void* d_out, int out_size, void* d_ws, size_t ws_size,
                              hipStream_t stream) {
    const float* X  = (const float*)d_in[0];   // (16384, 16, 8)
    const float* W  = (const float*)d_in[1];   // (32, 16, 8, 16)
    const float* Bi = (const float*)d_in[2];   // (32, 16, 1)
    float* Out = (float*)d_out;                // (16384, 32, 16)

    caps_v5<<<NBLK, NTH, 0, stream>>>(X, W, Bi, Out);
}